// Round 1
// baseline (219.616 us; speedup 1.0000x reference)
//
#include <hip/hip_runtime.h>
#include <hip/hip_bf16.h>
#include <stdint.h>

#define E_DIM 1280
#define KDIM 588
#define KPAD 608
#define M_TOTAL 6016
#define EMB_FLOATS (5*2048*1280)
#define MASK_FLOATS (5*2048*2048)

typedef __attribute__((ext_vector_type(8))) short bf16x8;
typedef __attribute__((ext_vector_type(4))) float f32x4;

__device__ __forceinline__ unsigned short f2bf(float f) {
    unsigned int u = __float_as_uint(f);
    u += 0x7fff + ((u >> 16) & 1);   // round-to-nearest-even
    return (unsigned short)(u >> 16);
}

// ---------------------------------------------------------------------------
// Kernel 1: extract 14x14 patches from 6 images into bf16 A[6016][608] (K-pad 588->608)
// row r -> (image, patch), col k = c*196 + iy*14 + ix
// ---------------------------------------------------------------------------
__global__ __launch_bounds__(256) void extract_patches(
    const float* __restrict__ i0, const float* __restrict__ i1,
    const float* __restrict__ i2, const float* __restrict__ i3,
    const float* __restrict__ i4, const float* __restrict__ i5,
    unsigned short* __restrict__ A)
{
    int idx = blockIdx.x * 256 + threadIdx.x;
    if (idx >= M_TOTAL * KPAD) return;
    int r = idx / KPAD;
    int k = idx - r * KPAD;
    unsigned short v = 0;
    if (k < KDIM) {
        const int rowOff[7] = {0,1024,2560,3136,3648,5248,6016};
        const int wA[6]     = {32,48,24,32,40,32};
        const int WA[6]     = {448,672,336,448,560,448};
        const int planeA[6] = {200704,301056,112896,100352,313600,150528};
        const float* imgs[6] = {i0,i1,i2,i3,i4,i5};
        int img = 0;
        #pragma unroll
        for (int i = 1; i < 6; ++i) if (r >= rowOff[i]) img = i;
        int ri = r - rowOff[img];
        int w = wA[img], W = WA[img], plane = planeA[img];
        int py = ri / w, px = ri - py * w;
        int c  = k / 196;
        int rem = k - c * 196;
        int iy = rem / 14, ix = rem - iy * 14;
        float pix = imgs[img][(size_t)c * plane + (size_t)(py*14 + iy) * W + (px*14 + ix)];
        v = f2bf(pix);
    }
    A[idx] = v;
}

// ---------------------------------------------------------------------------
// Kernel 2: conv_w (1280 x 588) fp32 -> bf16 Wbf[1280][608] (zero-padded K)
// ---------------------------------------------------------------------------
__global__ __launch_bounds__(256) void convert_w(
    const float* __restrict__ cw, unsigned short* __restrict__ Wb)
{
    int idx = blockIdx.x * 256 + threadIdx.x;
    if (idx >= E_DIM * KPAD) return;
    int e = idx / KPAD;
    int k = idx - e * KPAD;
    Wb[idx] = (k < KDIM) ? f2bf(cw[(size_t)e * KDIM + k]) : (unsigned short)0;
}

// ---------------------------------------------------------------------------
// Kernel 3: bf16 MFMA GEMM  C[6016][1280] = A[6016][608] * W^T[608][1280]
// 128x128 tile, BK=32, 4 waves (2x2), 4x4 16x16x32 MFMA per wave,
// global_load_lds width-16 staging.
// ---------------------------------------------------------------------------
__global__ __launch_bounds__(256) void gemm_bf16(
    const unsigned short* __restrict__ A,
    const unsigned short* __restrict__ Bm,
    float* __restrict__ C)
{
    __shared__ __align__(16) unsigned short As[128*32];
    __shared__ __align__(16) unsigned short Bs[128*32];
    const int t  = threadIdx.x;
    const int m0 = blockIdx.x * 128;
    const int n0 = blockIdx.y * 128;
    const int lane = t & 63;
    const int wv = t >> 6;
    const int wr = wv >> 1, wc = wv & 1;
    const int l16 = lane & 15, q = lane >> 4;

    f32x4 acc[4][4] = {};

    for (int kk = 0; kk < KPAD; kk += 32) {
        #pragma unroll
        for (int i = 0; i < 2; ++i) {
            int off = i * 4096 + t * 16;       // byte offset within tile
            int row = off >> 6;                // 64 B per row (32 bf16)
            int kb  = (off & 63) >> 1;         // element offset in k
            const unsigned short* ga = A  + (size_t)(m0 + row) * KPAD + kk + kb;
            __builtin_amdgcn_global_load_lds(
                (const __attribute__((address_space(1))) void*)ga,
                (__attribute__((address_space(3))) void*)((char*)As + off), 16, 0, 0);
            const unsigned short* gb = Bm + (size_t)(n0 + row) * KPAD + kk + kb;
            __builtin_amdgcn_global_load_lds(
                (const __attribute__((address_space(1))) void*)gb,
                (__attribute__((address_space(3))) void*)((char*)Bs + off), 16, 0, 0);
        }
        __syncthreads();

        bf16x8 af[4], bfr[4];
        #pragma unroll
        for (int mi = 0; mi < 4; ++mi)
            af[mi] = *(const bf16x8*)&As[(wr*64 + mi*16 + l16) * 32 + q * 8];
        #pragma unroll
        for (int ni = 0; ni < 4; ++ni)
            bfr[ni] = *(const bf16x8*)&Bs[(wc*64 + ni*16 + l16) * 32 + q * 8];
        #pragma unroll
        for (int mi = 0; mi < 4; ++mi)
            #pragma unroll
            for (int ni = 0; ni < 4; ++ni)
                acc[mi][ni] = __builtin_amdgcn_mfma_f32_16x16x32_bf16(
                    af[mi], bfr[ni], acc[mi][ni], 0, 0, 0);
        __syncthreads();
    }

    #pragma unroll
    for (int mi = 0; mi < 4; ++mi) {
        #pragma unroll
        for (int ni = 0; ni < 4; ++ni) {
            int col = n0 + wc*64 + ni*16 + l16;
            #pragma unroll
            for (int reg = 0; reg < 4; ++reg) {
                int rowr = m0 + wr*64 + mi*16 + q*4 + reg;
                C[(size_t)rowr * E_DIM + col] = acc[mi][ni][reg];
            }
        }
    }
}

// ---------------------------------------------------------------------------
// Kernel 4: epilogue — pos-embed bilinear interp + conv_b + LayerNorm + scatter
// one block (256 thr) per packed row
// ---------------------------------------------------------------------------
__global__ __launch_bounds__(256) void epilogue(
    const float* __restrict__ C, const float* __restrict__ pos_table,
    const float* __restrict__ conv_b,
    const float* __restrict__ ln_w, const float* __restrict__ ln_b,
    float* __restrict__ out)
{
    const int r = blockIdx.x;
    const int t = threadIdx.x;
    const int rowOff[7]  = {0,1024,2560,3136,3648,5248,6016};
    const int hA[6]      = {32,32,24,16,40,24};
    const int wA[6]      = {32,48,24,32,40,32};
    const int outBase[6] = {0, 2048, 4096, 4672, 6144, 8192}; // b*2048 + s

    int img = 0;
    #pragma unroll
    for (int i = 1; i < 6; ++i) if (r >= rowOff[i]) img = i;
    int ri = r - rowOff[img];
    int h = hA[img], w = wA[img];
    int y = ri / w, x = ri - y * w;

    float cy = fminf(fmaxf((y + 0.5f) * (32.0f / h) - 0.5f, 0.0f), 31.0f);
    float cx = fminf(fmaxf((x + 0.5f) * (32.0f / w) - 0.5f, 0.0f), 31.0f);
    int y0 = (int)floorf(cy); int y1 = min(y0 + 1, 31); float wy = cy - (float)y0;
    int x0 = (int)floorf(cx); int x1 = min(x0 + 1, 31); float wx = cx - (float)x0;

    const float* P00 = pos_table + (size_t)(1 + y0*32 + x0) * E_DIM;
    const float* P01 = pos_table + (size_t)(1 + y0*32 + x1) * E_DIM;
    const float* P10 = pos_table + (size_t)(1 + y1*32 + x0) * E_DIM;
    const float* P11 = pos_table + (size_t)(1 + y1*32 + x1) * E_DIM;

    float vals[5];
    float s = 0.f, s2 = 0.f;
    #pragma unroll
    for (int j = 0; j < 5; ++j) {
        int e = t + j * 256;
        float p = (1.f - wy) * ((1.f - wx) * P00[e] + wx * P01[e])
                +        wy  * ((1.f - wx) * P10[e] + wx * P11[e]);
        float v = C[(size_t)r * E_DIM + e] + conv_b[e] + p;
        vals[j] = v;
        s += v; s2 += v * v;
    }
    #pragma unroll
    for (int o = 32; o > 0; o >>= 1) {
        s  += __shfl_down(s,  o, 64);
        s2 += __shfl_down(s2, o, 64);
    }
    __shared__ float ls[8];
    int lane = t & 63, wvi = t >> 6;
    if (lane == 0) { ls[wvi] = s; ls[4 + wvi] = s2; }
    __syncthreads();
    if (t == 0) {
        float ts  = ls[0] + ls[1] + ls[2] + ls[3];
        float ts2 = ls[4] + ls[5] + ls[6] + ls[7];
        float m   = ts / 1280.f;
        float var = ts2 / 1280.f - m * m;
        ls[0] = m;
        ls[1] = 1.f / sqrtf(var + 1e-5f);
    }
    __syncthreads();
    float m = ls[0], inv = ls[1];
    size_t ob = (size_t)(outBase[img] + ri) * E_DIM;
    #pragma unroll
    for (int j = 0; j < 5; ++j) {
        int e = t + j * 256;
        out[ob + e] = (vals[j] - m) * inv * ln_w[e] + ln_b[e];
    }
}

// ---------------------------------------------------------------------------
// Kernel 5: fill — zeros for unfilled emb rows + block-diagonal mask (float4)
// ---------------------------------------------------------------------------
__global__ __launch_bounds__(256) void fill_rest(float4* __restrict__ out4)
{
    const int TOT4 = (EMB_FLOATS + MASK_FLOATS) / 4;
    int idx = blockIdx.x * 256 + threadIdx.x;
    if (idx >= TOT4) return;
    size_t flat = (size_t)idx * 4;
    if (flat < (size_t)EMB_FLOATS) {
        int row = (int)(flat / E_DIM);
        int b   = row >> 11;           // / 2048
        int seq = row & 2047;
        const int filled[5] = {1024,1536,1088,1600,768};
        if (seq >= filled[b]) {
            out4[idx] = make_float4(0.f, 0.f, 0.f, 0.f);
        }
    } else {
        size_t mrem = flat - (size_t)EMB_FLOATS;
        int b  = (int)(mrem >> 22);          // / (2048*2048)
        int rr = (int)(mrem >> 11) & 2047;
        int c0 = (int)(mrem & 2047);
        const int h0[5] = {1024,1536,576,1600,768};
        const int l1[5] = {0,0,576,0,0};
        const int h1[5] = {0,0,1088,0,0};
        bool rin0 = rr < h0[b];
        bool rin1 = (rr >= l1[b]) && (rr < h1[b]) && (h1[b] > 0);
        float4 v;
        float* vp = &v.x;
        #pragma unroll
        for (int j = 0; j < 4; ++j) {
            int c = c0 + j;
            bool on = (rin0 && c < h0[b]) ||
                      (rin1 && c >= l1[b] && c < h1[b]);
            vp[j] = on ? 1.f : 0.f;
        }
        out4[idx] = v;
    }
}

// ---------------------------------------------------------------------------
extern "C" void kernel_launch(void* const* d_in, const int* in_sizes, int n_in,
                              void* d_out, int out_size, void* d_ws, size_t ws_size,
                              hipStream_t stream) {
    const float* img0 = (const float*)d_in[0];
    const float* img1 = (const float*)d_in[1];
    const float* img2 = (const float*)d_in[2];
    const float* img3 = (const float*)d_in[3];
    const float* img4 = (const float*)d_in[4];
    const float* img5 = (const float*)d_in[5];
    const float* conv_w    = (const float*)d_in[6];
    const float* conv_b    = (const float*)d_in[7];
    const float* pos_table = (const float*)d_in[8];
    const float* ln_w      = (const float*)d_in[9];
    const float* ln_b      = (const float*)d_in[10];
    float* out = (float*)d_out;

    unsigned short* Abf = (unsigned short*)d_ws;                     // 6016*608*2 B
    unsigned short* Wbf = Abf + (size_t)M_TOTAL * KPAD;              // 1280*608*2 B
    float* Cbuf = out + EMB_FLOATS;   // temp fp32 C in mask region (overwritten by fill later)

    int nA = M_TOTAL * KPAD;
    extract_patches<<<(nA + 255) / 256, 256, 0, stream>>>(
        img0, img1, img2, img3, img4, img5, Abf);

    int nW = E_DIM * KPAD;
    convert_w<<<(nW + 255) / 256, 256, 0, stream>>>(conv_w, Wbf);

    dim3 g(M_TOTAL / 128, E_DIM / 128);   // 47 x 10
    gemm_bf16<<<g, 256, 0, stream>>>(Abf, Wbf, Cbuf);

    epilogue<<<M_TOTAL, 256, 0, stream>>>(Cbuf, pos_table, conv_b, ln_w, ln_b, out);

    int tot4 = (EMB_FLOATS + MASK_FLOATS) / 4;
    fill_rest<<<(tot4 + 255) / 256, 256, 0, stream>>>((float4*)out);
}

// Round 2
// 209.950 us; speedup vs baseline: 1.0460x; 1.0460x over previous
//
#include <hip/hip_runtime.h>
#include <hip/hip_bf16.h>
#include <stdint.h>

#define E_DIM 1280
#define KDIM 588
#define KPAD 608
#define M_TOTAL 6016
#define EMB_FLOATS (5*2048*1280)
#define MASK_FLOATS (5*2048*2048)

// fused kernel block ranges (256-thread blocks)
#define EXT_BLOCKS  14288              // 6016*608/256
#define CW_BLOCKS   3040               // 1280*608/256
#define ZERO_BLOCKS 5280               // 4224*320/256  (4224 zero rows x 320 float4)
#define MASK_BLOCKS 20480              // 5*2048*2048/4/256
#define TOTAL_BLOCKS (EXT_BLOCKS + CW_BLOCKS + ZERO_BLOCKS + MASK_BLOCKS)

typedef __attribute__((ext_vector_type(8))) short bf16x8;
typedef __attribute__((ext_vector_type(4))) float f32x4;

__device__ __forceinline__ unsigned short f2bf(float f) {
    unsigned int u = __float_as_uint(f);
    u += 0x7fff + ((u >> 16) & 1);   // round-to-nearest-even
    return (unsigned short)(u >> 16);
}

// Per-image extract with COMPILE-TIME divisors (magic-mul, no scratch, no v_rcp)
template<int PW, int IMGW, int PLANE>
__device__ __forceinline__ void do_extract(const float* __restrict__ img,
                                           unsigned short* __restrict__ A,
                                           int flatBase, int local)
{
    int r_local = local / KPAD;
    int k = local - r_local * KPAD;
    unsigned short v = 0;
    if (k < KDIM) {
        int py = r_local / PW;  int px = r_local - py * PW;
        int c  = k / 196;       int rem = k - c * 196;
        int iy = rem / 14;      int ix = rem - iy * 14;
        v = f2bf(img[(size_t)c * PLANE + (size_t)(py*14 + iy) * IMGW + (px*14 + ix)]);
    }
    A[flatBase + local] = v;
}

// ---------------------------------------------------------------------------
// Kernel 1 (fused): patch extract (6 imgs) + conv_w->bf16 + emb-zero fill +
// mask fill. All block-range partitioned; img selection is block-uniform.
// ---------------------------------------------------------------------------
__global__ __launch_bounds__(256) void fused_prep(
    const float* __restrict__ i0, const float* __restrict__ i1,
    const float* __restrict__ i2, const float* __restrict__ i3,
    const float* __restrict__ i4, const float* __restrict__ i5,
    const float* __restrict__ conv_w,
    unsigned short* __restrict__ A, unsigned short* __restrict__ Wb,
    float4* __restrict__ out4)
{
    const int bid = blockIdx.x;
    const int t = threadIdx.x;

    if (bid < EXT_BLOCKS) {
        // cumulative block starts per image: 0,2432,6080,7448,8664,12464
        if (bid < 2432) {
            int local = bid * 256 + t;
            do_extract<32,448,200704>(i0, A, 0, local);
        } else if (bid < 6080) {
            int local = (bid - 2432) * 256 + t;
            do_extract<48,672,301056>(i1, A, 2432*256, local);
        } else if (bid < 7448) {
            int local = (bid - 6080) * 256 + t;
            do_extract<24,336,112896>(i2, A, 6080*256, local);
        } else if (bid < 8664) {
            int local = (bid - 7448) * 256 + t;
            do_extract<32,448,100352>(i3, A, 7448*256, local);
        } else if (bid < 12464) {
            int local = (bid - 8664) * 256 + t;
            do_extract<40,560,313600>(i4, A, 8664*256, local);
        } else {
            int local = (bid - 12464) * 256 + t;
            do_extract<32,448,150528>(i5, A, 12464*256, local);
        }
    } else if (bid < EXT_BLOCKS + CW_BLOCKS) {
        int idx = (bid - EXT_BLOCKS) * 256 + t;
        int e = idx / KPAD;
        int k = idx - e * KPAD;
        Wb[idx] = (k < KDIM) ? f2bf(conv_w[(size_t)e * KDIM + k]) : (unsigned short)0;
    } else if (bid < EXT_BLOCKS + CW_BLOCKS + ZERO_BLOCKS) {
        // zero the unfilled emb rows (4224 rows x 320 float4)
        int idx = (bid - EXT_BLOCKS - CW_BLOCKS) * 256 + t;
        int zrow = idx / 320;
        int c4   = idx - zrow * 320;
        // cumulative zero-row counts: 1024,1536,2496,2944,4224
        int b, rowInB;
        if      (zrow < 1024) { b = 0; rowInB = 1024 + zrow; }
        else if (zrow < 1536) { b = 1; rowInB = 1536 + (zrow - 1024); }
        else if (zrow < 2496) { b = 2; rowInB = 1088 + (zrow - 1536); }
        else if (zrow < 2944) { b = 3; rowInB = 1600 + (zrow - 2496); }
        else                  { b = 4; rowInB =  768 + (zrow - 2944); }
        size_t o4 = ((size_t)(b * 2048 + rowInB) * E_DIM) / 4 + c4;
        out4[o4] = make_float4(0.f, 0.f, 0.f, 0.f);
    } else {
        // mask fill: 5 x 2048 x 2048 floats, one float4 per thread
        int m4 = (bid - EXT_BLOCKS - CW_BLOCKS - ZERO_BLOCKS) * 256 + t;
        int b  = m4 >> 20;             // 1048576 float4 per batch mask
        int rr = (m4 >> 9) & 2047;     // 512 float4 per row
        int c0 = (m4 & 511) * 4;
        int h0 = (b == 0) ? 1024 : (b == 1) ? 1536 : (b == 2) ? 576 : (b == 3) ? 1600 : 768;
        bool on = (rr < h0 && c0 < h0);
        if (b == 2) on = on || (rr >= 576 && rr < 1088 && c0 >= 576 && c0 < 1088);
        float f = on ? 1.f : 0.f;
        out4[(size_t)(EMB_FLOATS / 4) + m4] = make_float4(f, f, f, f);
    }
}

// ---------------------------------------------------------------------------
// Kernel 2: bf16 MFMA GEMM  C[6016][1280] = A[6016][608] * W^T[608][1280]
// ---------------------------------------------------------------------------
__global__ __launch_bounds__(256) void gemm_bf16(
    const unsigned short* __restrict__ A,
    const unsigned short* __restrict__ Bm,
    float* __restrict__ C)
{
    __shared__ __align__(16) unsigned short As[128*32];
    __shared__ __align__(16) unsigned short Bs[128*32];
    const int t  = threadIdx.x;
    const int m0 = blockIdx.x * 128;
    const int n0 = blockIdx.y * 128;
    const int lane = t & 63;
    const int wv = t >> 6;
    const int wr = wv >> 1, wc = wv & 1;
    const int l16 = lane & 15, q = lane >> 4;

    f32x4 acc[4][4] = {};

    for (int kk = 0; kk < KPAD; kk += 32) {
        #pragma unroll
        for (int i = 0; i < 2; ++i) {
            int off = i * 4096 + t * 16;
            int row = off >> 6;
            int kb  = (off & 63) >> 1;
            const unsigned short* ga = A  + (size_t)(m0 + row) * KPAD + kk + kb;
            __builtin_amdgcn_global_load_lds(
                (const __attribute__((address_space(1))) void*)ga,
                (__attribute__((address_space(3))) void*)((char*)As + off), 16, 0, 0);
            const unsigned short* gb = Bm + (size_t)(n0 + row) * KPAD + kk + kb;
            __builtin_amdgcn_global_load_lds(
                (const __attribute__((address_space(1))) void*)gb,
                (__attribute__((address_space(3))) void*)((char*)Bs + off), 16, 0, 0);
        }
        __syncthreads();

        bf16x8 af[4], bfr[4];
        #pragma unroll
        for (int mi = 0; mi < 4; ++mi)
            af[mi] = *(const bf16x8*)&As[(wr*64 + mi*16 + l16) * 32 + q * 8];
        #pragma unroll
        for (int ni = 0; ni < 4; ++ni)
            bfr[ni] = *(const bf16x8*)&Bs[(wc*64 + ni*16 + l16) * 32 + q * 8];
        #pragma unroll
        for (int mi = 0; mi < 4; ++mi)
            #pragma unroll
            for (int ni = 0; ni < 4; ++ni)
                acc[mi][ni] = __builtin_amdgcn_mfma_f32_16x16x32_bf16(
                    af[mi], bfr[ni], acc[mi][ni], 0, 0, 0);
        __syncthreads();
    }

    #pragma unroll
    for (int mi = 0; mi < 4; ++mi) {
        #pragma unroll
        for (int ni = 0; ni < 4; ++ni) {
            int col = n0 + wc*64 + ni*16 + l16;
            #pragma unroll
            for (int reg = 0; reg < 4; ++reg) {
                int rowr = m0 + wr*64 + mi*16 + q*4 + reg;
                C[(size_t)rowr * E_DIM + col] = acc[mi][ni][reg];
            }
        }
    }
}

// ---------------------------------------------------------------------------
// Kernel 3: epilogue — pos-embed bilinear + conv_b + LayerNorm + scatter
// one block of 320 threads per packed row, float4 throughout
// ---------------------------------------------------------------------------
__global__ __launch_bounds__(320) void epilogue(
    const float* __restrict__ C, const float* __restrict__ pos_table,
    const float* __restrict__ conv_b,
    const float* __restrict__ ln_w, const float* __restrict__ ln_b,
    float* __restrict__ out)
{
    const int r = blockIdx.x;
    const int t = threadIdx.x;   // 0..319

    // block-uniform image select (compare chain, no arrays)
    int img     = (r < 1024) ? 0 : (r < 2560) ? 1 : (r < 3136) ? 2 : (r < 3648) ? 3 : (r < 5248) ? 4 : 5;
    int rowOff  = (img == 0) ? 0 : (img == 1) ? 1024 : (img == 2) ? 2560 : (img == 3) ? 3136 : (img == 4) ? 3648 : 5248;
    int h       = (img == 0) ? 32 : (img == 1) ? 32 : (img == 2) ? 24 : (img == 3) ? 16 : (img == 4) ? 40 : 24;
    int w       = (img == 0) ? 32 : (img == 1) ? 48 : (img == 2) ? 24 : (img == 3) ? 32 : (img == 4) ? 40 : 32;
    int outBase = (img == 0) ? 0 : (img == 1) ? 2048 : (img == 2) ? 4096 : (img == 3) ? 4672 : (img == 4) ? 6144 : 8192;

    int ri = r - rowOff;
    int y = ri / w, x = ri - y * w;

    float cy = fminf(fmaxf((y + 0.5f) * (32.0f / h) - 0.5f, 0.0f), 31.0f);
    float cx = fminf(fmaxf((x + 0.5f) * (32.0f / w) - 0.5f, 0.0f), 31.0f);
    int y0 = (int)floorf(cy); int y1 = min(y0 + 1, 31); float wy = cy - (float)y0;
    int x0 = (int)floorf(cx); int x1 = min(x0 + 1, 31); float wx = cx - (float)x0;

    const float4* P00 = (const float4*)(pos_table + (size_t)(1 + y0*32 + x0) * E_DIM);
    const float4* P01 = (const float4*)(pos_table + (size_t)(1 + y0*32 + x1) * E_DIM);
    const float4* P10 = (const float4*)(pos_table + (size_t)(1 + y1*32 + x0) * E_DIM);
    const float4* P11 = (const float4*)(pos_table + (size_t)(1 + y1*32 + x1) * E_DIM);
    const float4* C4  = (const float4*)(C + (size_t)r * E_DIM);
    const float4* B4  = (const float4*)conv_b;

    float w00 = (1.f - wy) * (1.f - wx), w01 = (1.f - wy) * wx;
    float w10 = wy * (1.f - wx),         w11 = wy * wx;

    float4 a = P00[t], b2 = P01[t], c2 = P10[t], d2 = P11[t];
    float4 cv = C4[t], bv = B4[t];
    float4 v;
    v.x = cv.x + bv.x + w00*a.x + w01*b2.x + w10*c2.x + w11*d2.x;
    v.y = cv.y + bv.y + w00*a.y + w01*b2.y + w10*c2.y + w11*d2.y;
    v.z = cv.z + bv.z + w00*a.z + w01*b2.z + w10*c2.z + w11*d2.z;
    v.w = cv.w + bv.w + w00*a.w + w01*b2.w + w10*c2.w + w11*d2.w;

    float s  = v.x + v.y + v.z + v.w;
    float s2 = v.x*v.x + v.y*v.y + v.z*v.z + v.w*v.w;
    #pragma unroll
    for (int o = 32; o > 0; o >>= 1) {
        s  += __shfl_down(s,  o, 64);
        s2 += __shfl_down(s2, o, 64);
    }
    __shared__ float ls[12];
    int lane = t & 63, wvi = t >> 6;   // 5 waves
    if (lane == 0) { ls[wvi] = s; ls[6 + wvi] = s2; }
    __syncthreads();
    if (t == 0) {
        float ts  = ls[0] + ls[1] + ls[2] + ls[3] + ls[4];
        float ts2 = ls[6] + ls[7] + ls[8] + ls[9] + ls[10];
        float m   = ts / 1280.f;
        float var = ts2 / 1280.f - m * m;
        ls[0] = m;
        ls[1] = 1.f / sqrtf(var + 1e-5f);
    }
    __syncthreads();
    float m = ls[0], inv = ls[1];

    float4 g = ((const float4*)ln_w)[t], be = ((const float4*)ln_b)[t];
    float4 o4;
    o4.x = (v.x - m) * inv * g.x + be.x;
    o4.y = (v.y - m) * inv * g.y + be.y;
    o4.z = (v.z - m) * inv * g.z + be.z;
    o4.w = (v.w - m) * inv * g.w + be.w;
    ((float4*)(out + (size_t)(outBase + ri) * E_DIM))[t] = o4;
}

// ---------------------------------------------------------------------------
extern "C" void kernel_launch(void* const* d_in, const int* in_sizes, int n_in,
                              void* d_out, int out_size, void* d_ws, size_t ws_size,
                              hipStream_t stream) {
    const float* img0 = (const float*)d_in[0];
    const float* img1 = (const float*)d_in[1];
    const float* img2 = (const float*)d_in[2];
    const float* img3 = (const float*)d_in[3];
    const float* img4 = (const float*)d_in[4];
    const float* img5 = (const float*)d_in[5];
    const float* conv_w    = (const float*)d_in[6];
    const float* conv_b    = (const float*)d_in[7];
    const float* pos_table = (const float*)d_in[8];
    const float* ln_w      = (const float*)d_in[9];
    const float* ln_b      = (const float*)d_in[10];
    float* out = (float*)d_out;

    unsigned short* Abf = (unsigned short*)d_ws;                 // 6016*608*2 B = 7.3 MB
    unsigned short* Wbf = Abf + (size_t)M_TOTAL * KPAD;          // 1280*608*2 B = 1.5 MB
    float* Cbuf = (float*)(Wbf + (size_t)E_DIM * KPAD);          // 6016*1280*4 B = 30.8 MB (ws)

    fused_prep<<<TOTAL_BLOCKS, 256, 0, stream>>>(
        img0, img1, img2, img3, img4, img5, conv_w, Abf, Wbf, (float4*)out);

    dim3 g(M_TOTAL / 128, E_DIM / 128);   // 47 x 10
    gemm_bf16<<<g, 256, 0, stream>>>(Abf, Wbf, Cbuf);

    epilogue<<<M_TOTAL, 320, 0, stream>>>(Cbuf, pos_table, conv_b, ln_w, ln_b, out);
}

// Round 3
// 206.371 us; speedup vs baseline: 1.0642x; 1.0173x over previous
//
#include <hip/hip_runtime.h>
#include <hip/hip_bf16.h>
#include <stdint.h>

#define E_DIM 1280
#define KDIM 588
#define KPAD 608
#define M_TOTAL 6016
#define EMB_FLOATS (5*2048*1280)
#define MASK_FLOATS (5*2048*2048)

// fused prep: block ranges (256 threads, 4x work per thread)
// extract: ushort4 units, per-image rows*152 u4
#define EXT_BLOCKS  3572   // 608+912+342+304+950+456
#define CW_BLOCKS   760    // 1280*608/4/256
#define ZERO_BLOCKS 1320   // 4224*320 float4 /1024
#define MASK_BLOCKS 5120   // 5*2048*512 float4 /1024
#define TOTAL_BLOCKS (EXT_BLOCKS + CW_BLOCKS + ZERO_BLOCKS + MASK_BLOCKS)

typedef __attribute__((ext_vector_type(8))) short bf16x8;
typedef __attribute__((ext_vector_type(4))) float f32x4;

struct us4 { unsigned short x, y, z, w; };

__device__ __forceinline__ unsigned short f2bf(float f) {
    unsigned int u = __float_as_uint(f);
    u += 0x7fff + ((u >> 16) & 1);   // round-to-nearest-even
    return (unsigned short)(u >> 16);
}

// Extract 4 consecutive k-elements for one patch row. Compile-time divisors.
template<int PW, int IMGW, int PLANE>
__device__ __forceinline__ void do_extract4(const float* __restrict__ img,
                                            us4* __restrict__ A4,
                                            int base_u4, int local_u4)
{
    int r_local = local_u4 / 152;          // 152 u4 per row (KPAD/4)
    int k4 = (local_u4 - r_local * 152) * 4;
    us4 v = {0, 0, 0, 0};
    if (k4 < KDIM) {                        // KDIM%4==0 -> whole u4 valid or pad
        int py = r_local / PW;  int px = r_local - py * PW;
        int c   = k4 / 196;                 // 196%4==0 -> uniform across the 4
        int rem0 = k4 - c * 196;
        const float* p = img + (size_t)c * PLANE;
        unsigned short o[4];
        #pragma unroll
        for (int j = 0; j < 4; ++j) {
            int rem = rem0 + j;
            int iy = rem / 14, ix = rem - iy * 14;
            o[j] = f2bf(p[(size_t)(py*14 + iy) * IMGW + (px*14 + ix)]);
        }
        v.x = o[0]; v.y = o[1]; v.z = o[2]; v.w = o[3];
    }
    A4[base_u4 + local_u4] = v;
}

// ---------------------------------------------------------------------------
// Kernel 1 (fused): patch extract + conv_w->bf16 + emb-zero + mask fill.
// 4x work per thread everywhere.
// ---------------------------------------------------------------------------
__global__ __launch_bounds__(256) void fused_prep(
    const float* __restrict__ i0, const float* __restrict__ i1,
    const float* __restrict__ i2, const float* __restrict__ i3,
    const float* __restrict__ i4, const float* __restrict__ i5,
    const float* __restrict__ conv_w,
    us4* __restrict__ A4, us4* __restrict__ W4,
    float4* __restrict__ out4)
{
    const int bid = blockIdx.x;
    const int t = threadIdx.x;

    if (bid < EXT_BLOCKS) {
        // cumulative block starts: 0,608,1520,1862,2166,3116
        if (bid < 608) {
            do_extract4<32,448,200704>(i0, A4, 0,      bid * 256 + t);
        } else if (bid < 1520) {
            do_extract4<48,672,301056>(i1, A4, 155648, (bid - 608) * 256 + t);
        } else if (bid < 1862) {
            do_extract4<24,336,112896>(i2, A4, 389120, (bid - 1520) * 256 + t);
        } else if (bid < 2166) {
            do_extract4<32,448,100352>(i3, A4, 476672, (bid - 1862) * 256 + t);
        } else if (bid < 3116) {
            do_extract4<40,560,313600>(i4, A4, 554496, (bid - 2166) * 256 + t);
        } else {
            do_extract4<32,448,150528>(i5, A4, 797696, (bid - 3116) * 256 + t);
        }
    } else if (bid < EXT_BLOCKS + CW_BLOCKS) {
        int idx4 = (bid - EXT_BLOCKS) * 256 + t;
        int e  = idx4 / 152;
        int k4 = (idx4 - e * 152) * 4;
        us4 v = {0, 0, 0, 0};
        if (k4 < KDIM) {
            const float* p = conv_w + (size_t)e * KDIM + k4;
            v.x = f2bf(p[0]); v.y = f2bf(p[1]); v.z = f2bf(p[2]); v.w = f2bf(p[3]);
        }
        W4[idx4] = v;
    } else if (bid < EXT_BLOCKS + CW_BLOCKS + ZERO_BLOCKS) {
        int base = (bid - EXT_BLOCKS - CW_BLOCKS) * 1024 + t;
        #pragma unroll
        for (int j = 0; j < 4; ++j) {
            int idx = base + j * 256;               // < 1351680
            int zrow = idx / 320;
            int c4   = idx - zrow * 320;
            int b, rowInB;
            if      (zrow < 1024) { b = 0; rowInB = 1024 + zrow; }
            else if (zrow < 1536) { b = 1; rowInB = 1536 + (zrow - 1024); }
            else if (zrow < 2496) { b = 2; rowInB = 1088 + (zrow - 1536); }
            else if (zrow < 2944) { b = 3; rowInB = 1600 + (zrow - 2496); }
            else                  { b = 4; rowInB =  768 + (zrow - 2944); }
            size_t o4 = ((size_t)(b * 2048 + rowInB) * E_DIM) / 4 + c4;
            out4[o4] = make_float4(0.f, 0.f, 0.f, 0.f);
        }
    } else {
        int base = (bid - EXT_BLOCKS - CW_BLOCKS - ZERO_BLOCKS) * 1024 + t;
        #pragma unroll
        for (int j = 0; j < 4; ++j) {
            int m4 = base + j * 256;
            int b  = m4 >> 20;
            int rr = (m4 >> 9) & 2047;
            int c0 = (m4 & 511) * 4;
            int h0 = (b == 0) ? 1024 : (b == 1) ? 1536 : (b == 2) ? 576 : (b == 3) ? 1600 : 768;
            bool on = (rr < h0 && c0 < h0);
            if (b == 2) on = on || (rr >= 576 && rr < 1088 && c0 >= 576 && c0 < 1088);
            float f = on ? 1.f : 0.f;
            out4[(size_t)(EMB_FLOATS / 4) + m4] = make_float4(f, f, f, f);
        }
    }
}

// ---------------------------------------------------------------------------
// Kernel 2: bf16 MFMA GEMM  C[6016][1280] = A[6016][608] * W^T[608][1280]
// ---------------------------------------------------------------------------
__global__ __launch_bounds__(256) void gemm_bf16(
    const unsigned short* __restrict__ A,
    const unsigned short* __restrict__ Bm,
    float* __restrict__ C)
{
    __shared__ __align__(16) unsigned short As[128*32];
    __shared__ __align__(16) unsigned short Bs[128*32];
    const int t  = threadIdx.x;
    const int m0 = blockIdx.x * 128;
    const int n0 = blockIdx.y * 128;
    const int lane = t & 63;
    const int wv = t >> 6;
    const int wr = wv >> 1, wc = wv & 1;
    const int l16 = lane & 15, q = lane >> 4;

    f32x4 acc[4][4] = {};

    for (int kk = 0; kk < KPAD; kk += 32) {
        #pragma unroll
        for (int i = 0; i < 2; ++i) {
            int off = i * 4096 + t * 16;
            int row = off >> 6;
            int kb  = (off & 63) >> 1;
            const unsigned short* ga = A  + (size_t)(m0 + row) * KPAD + kk + kb;
            __builtin_amdgcn_global_load_lds(
                (const __attribute__((address_space(1))) void*)ga,
                (__attribute__((address_space(3))) void*)((char*)As + off), 16, 0, 0);
            const unsigned short* gb = Bm + (size_t)(n0 + row) * KPAD + kk + kb;
            __builtin_amdgcn_global_load_lds(
                (const __attribute__((address_space(1))) void*)gb,
                (__attribute__((address_space(3))) void*)((char*)Bs + off), 16, 0, 0);
        }
        __syncthreads();

        bf16x8 af[4], bfr[4];
        #pragma unroll
        for (int mi = 0; mi < 4; ++mi)
            af[mi] = *(const bf16x8*)&As[(wr*64 + mi*16 + l16) * 32 + q * 8];
        #pragma unroll
        for (int ni = 0; ni < 4; ++ni)
            bfr[ni] = *(const bf16x8*)&Bs[(wc*64 + ni*16 + l16) * 32 + q * 8];
        #pragma unroll
        for (int mi = 0; mi < 4; ++mi)
            #pragma unroll
            for (int ni = 0; ni < 4; ++ni)
                acc[mi][ni] = __builtin_amdgcn_mfma_f32_16x16x32_bf16(
                    af[mi], bfr[ni], acc[mi][ni], 0, 0, 0);
        __syncthreads();
    }

    #pragma unroll
    for (int mi = 0; mi < 4; ++mi) {
        #pragma unroll
        for (int ni = 0; ni < 4; ++ni) {
            int col = n0 + wc*64 + ni*16 + l16;
            #pragma unroll
            for (int reg = 0; reg < 4; ++reg) {
                int rowr = m0 + wr*64 + mi*16 + q*4 + reg;
                C[(size_t)rowr * E_DIM + col] = acc[mi][ni][reg];
            }
        }
    }
}

// ---------------------------------------------------------------------------
// Kernel 3: epilogue — wave-per-row, 4 rows per 256-thr block, shuffle-only LN
// ---------------------------------------------------------------------------
__global__ __launch_bounds__(256) void epilogue(
    const float* __restrict__ C, const float* __restrict__ pos_table,
    const float* __restrict__ conv_b,
    const float* __restrict__ ln_w, const float* __restrict__ ln_b,
    float* __restrict__ out)
{
    const int t = threadIdx.x;
    const int wave = t >> 6, lane = t & 63;
    const int r = blockIdx.x * 4 + wave;          // 0..6015

    int img     = (r < 1024) ? 0 : (r < 2560) ? 1 : (r < 3136) ? 2 : (r < 3648) ? 3 : (r < 5248) ? 4 : 5;
    int rowOff  = (img == 0) ? 0 : (img == 1) ? 1024 : (img == 2) ? 2560 : (img == 3) ? 3136 : (img == 4) ? 3648 : 5248;
    int h       = (img == 0) ? 32 : (img == 1) ? 32 : (img == 2) ? 24 : (img == 3) ? 16 : (img == 4) ? 40 : 24;
    int w       = (img == 0) ? 32 : (img == 1) ? 48 : (img == 2) ? 24 : (img == 3) ? 32 : (img == 4) ? 40 : 32;
    int outBase = (img == 0) ? 0 : (img == 1) ? 2048 : (img == 2) ? 4096 : (img == 3) ? 4672 : (img == 4) ? 6144 : 8192;

    int ri = r - rowOff;
    int y = ri / w, x = ri - y * w;

    float cy = fminf(fmaxf((y + 0.5f) * (32.0f / h) - 0.5f, 0.0f), 31.0f);
    float cx = fminf(fmaxf((x + 0.5f) * (32.0f / w) - 0.5f, 0.0f), 31.0f);
    int y0 = (int)floorf(cy); int y1 = min(y0 + 1, 31); float wy = cy - (float)y0;
    int x0 = (int)floorf(cx); int x1 = min(x0 + 1, 31); float wx = cx - (float)x0;

    const float4* P00 = (const float4*)(pos_table + (size_t)(1 + y0*32 + x0) * E_DIM);
    const float4* P01 = (const float4*)(pos_table + (size_t)(1 + y0*32 + x1) * E_DIM);
    const float4* P10 = (const float4*)(pos_table + (size_t)(1 + y1*32 + x0) * E_DIM);
    const float4* P11 = (const float4*)(pos_table + (size_t)(1 + y1*32 + x1) * E_DIM);
    const float4* C4  = (const float4*)(C + (size_t)r * E_DIM);
    const float4* B4  = (const float4*)conv_b;

    float w00 = (1.f - wy) * (1.f - wx), w01 = (1.f - wy) * wx;
    float w10 = wy * (1.f - wx),         w11 = wy * wx;

    float4 vals[5];
    float s = 0.f, s2 = 0.f;
    #pragma unroll
    for (int j = 0; j < 5; ++j) {
        int e4 = lane + j * 64;
        float4 a = P00[e4], b2 = P01[e4], c2 = P10[e4], d2 = P11[e4];
        float4 cv = C4[e4], bv = B4[e4];
        float4 v;
        v.x = cv.x + bv.x + w00*a.x + w01*b2.x + w10*c2.x + w11*d2.x;
        v.y = cv.y + bv.y + w00*a.y + w01*b2.y + w10*c2.y + w11*d2.y;
        v.z = cv.z + bv.z + w00*a.z + w01*b2.z + w10*c2.z + w11*d2.z;
        v.w = cv.w + bv.w + w00*a.w + w01*b2.w + w10*c2.w + w11*d2.w;
        vals[j] = v;
        s  += v.x + v.y + v.z + v.w;
        s2 += v.x*v.x + v.y*v.y + v.z*v.z + v.w*v.w;
    }
    #pragma unroll
    for (int m = 32; m > 0; m >>= 1) {
        s  += __shfl_xor(s,  m, 64);
        s2 += __shfl_xor(s2, m, 64);
    }
    float mean = s / 1280.f;
    float var  = s2 / 1280.f - mean * mean;
    float inv  = 1.f / sqrtf(var + 1e-5f);

    float4* O4 = (float4*)(out + (size_t)(outBase + ri) * E_DIM);
    #pragma unroll
    for (int j = 0; j < 5; ++j) {
        int e4 = lane + j * 64;
        float4 g = ((const float4*)ln_w)[e4], be = ((const float4*)ln_b)[e4];
        float4 v = vals[j], o4;
        o4.x = (v.x - mean) * inv * g.x + be.x;
        o4.y = (v.y - mean) * inv * g.y + be.y;
        o4.z = (v.z - mean) * inv * g.z + be.z;
        o4.w = (v.w - mean) * inv * g.w + be.w;
        O4[e4] = o4;
    }
}

// ---------------------------------------------------------------------------
extern "C" void kernel_launch(void* const* d_in, const int* in_sizes, int n_in,
                              void* d_out, int out_size, void* d_ws, size_t ws_size,
                              hipStream_t stream) {
    const float* img0 = (const float*)d_in[0];
    const float* img1 = (const float*)d_in[1];
    const float* img2 = (const float*)d_in[2];
    const float* img3 = (const float*)d_in[3];
    const float* img4 = (const float*)d_in[4];
    const float* img5 = (const float*)d_in[5];
    const float* conv_w    = (const float*)d_in[6];
    const float* conv_b    = (const float*)d_in[7];
    const float* pos_table = (const float*)d_in[8];
    const float* ln_w      = (const float*)d_in[9];
    const float* ln_b      = (const float*)d_in[10];
    float* out = (float*)d_out;

    unsigned short* Abf = (unsigned short*)d_ws;                 // 7.3 MB
    unsigned short* Wbf = Abf + (size_t)M_TOTAL * KPAD;          // 1.5 MB
    float* Cbuf = (float*)(Wbf + (size_t)E_DIM * KPAD);          // 30.8 MB

    fused_prep<<<TOTAL_BLOCKS, 256, 0, stream>>>(
        img0, img1, img2, img3, img4, img5, conv_w,
        (us4*)Abf, (us4*)Wbf, (float4*)out);

    dim3 g(M_TOTAL / 128, E_DIM / 128);   // 47 x 10
    gemm_bf16<<<g, 256, 0, stream>>>(Abf, Wbf, Cbuf);

    epilogue<<<1504, 256, 0, stream>>>(Cbuf, pos_table, conv_b, ln_w, ln_b, out);
}

// Round 4
// 203.376 us; speedup vs baseline: 1.0798x; 1.0147x over previous
//
#include <hip/hip_runtime.h>
#include <hip/hip_bf16.h>
#include <stdint.h>

#define E_DIM 1280
#define KDIM 588
#define KPAD 608
#define M_TOTAL 6016
#define EMB_FLOATS (5*2048*1280)
#define MASK_FLOATS (5*2048*2048)

// prep kernel (256 thr): extract + convW only
#define EXT_BLOCKS  3572   // 608+912+342+304+950+456
#define CW_BLOCKS   760    // 1280*608/4/256
#define PREP_BLOCKS (EXT_BLOCKS + CW_BLOCKS)

// fused gemm kernel (512 thr)
#define GEMM_BLOCKS 188            // 6016/32
#define ZERO_BLOCKS2 660           // 1351680 float4 / 2048
#define MASK_BLOCKS2 2560          // 5242880 float4 / 2048
#define FUSED_BLOCKS (GEMM_BLOCKS + ZERO_BLOCKS2 + MASK_BLOCKS2)

typedef __attribute__((ext_vector_type(8))) short bf16x8;
typedef __attribute__((ext_vector_type(4))) float f32x4;

struct us4 { unsigned short x, y, z, w; };

__device__ __forceinline__ unsigned short f2bf(float f) {
    unsigned int u = __float_as_uint(f);
    u += 0x7fff + ((u >> 16) & 1);
    return (unsigned short)(u >> 16);
}

template<int PW, int IMGW, int PLANE>
__device__ __forceinline__ void do_extract4(const float* __restrict__ img,
                                            us4* __restrict__ A4,
                                            int base_u4, int local_u4)
{
    int r_local = local_u4 / 152;
    int k4 = (local_u4 - r_local * 152) * 4;
    us4 v = {0, 0, 0, 0};
    if (k4 < KDIM) {
        int py = r_local / PW;  int px = r_local - py * PW;
        int c   = k4 / 196;
        int rem0 = k4 - c * 196;
        const float* p = img + (size_t)c * PLANE;
        unsigned short o[4];
        #pragma unroll
        for (int j = 0; j < 4; ++j) {
            int rem = rem0 + j;
            int iy = rem / 14, ix = rem - iy * 14;
            o[j] = f2bf(p[(size_t)(py*14 + iy) * IMGW + (px*14 + ix)]);
        }
        v.x = o[0]; v.y = o[1]; v.z = o[2]; v.w = o[3];
    }
    A4[base_u4 + local_u4] = v;
}

// ---------------------------------------------------------------------------
// Kernel 1: patch extract (6 imgs) + conv_w -> bf16
// ---------------------------------------------------------------------------
__global__ __launch_bounds__(256) void prep(
    const float* __restrict__ i0, const float* __restrict__ i1,
    const float* __restrict__ i2, const float* __restrict__ i3,
    const float* __restrict__ i4, const float* __restrict__ i5,
    const float* __restrict__ conv_w,
    us4* __restrict__ A4, us4* __restrict__ W4)
{
    const int bid = blockIdx.x;
    const int t = threadIdx.x;
    if (bid < EXT_BLOCKS) {
        if (bid < 608) {
            do_extract4<32,448,200704>(i0, A4, 0,      bid * 256 + t);
        } else if (bid < 1520) {
            do_extract4<48,672,301056>(i1, A4, 155648, (bid - 608) * 256 + t);
        } else if (bid < 1862) {
            do_extract4<24,336,112896>(i2, A4, 389120, (bid - 1520) * 256 + t);
        } else if (bid < 2166) {
            do_extract4<32,448,100352>(i3, A4, 476672, (bid - 1862) * 256 + t);
        } else if (bid < 3116) {
            do_extract4<40,560,313600>(i4, A4, 554496, (bid - 2166) * 256 + t);
        } else {
            do_extract4<32,448,150528>(i5, A4, 797696, (bid - 3116) * 256 + t);
        }
    } else {
        int idx4 = (bid - EXT_BLOCKS) * 256 + t;
        int e  = idx4 / 152;
        int k4 = (idx4 - e * 152) * 4;
        us4 v = {0, 0, 0, 0};
        if (k4 < KDIM) {
            const float* p = conv_w + (size_t)e * KDIM + k4;
            v.x = f2bf(p[0]); v.y = f2bf(p[1]); v.z = f2bf(p[2]); v.w = f2bf(p[3]);
        }
        W4[idx4] = v;
    }
}

// ---------------------------------------------------------------------------
// Kernel 2 (fused): GEMM(M=32 x N=1280 per block, no-LDS K-loop, frags from
// L2) + pos-embed bilinear + conv_b + LayerNorm + scatter.  Extra blocks do
// the emb-zero and mask fills, co-scheduled with the MFMA blocks.
// ---------------------------------------------------------------------------
__global__ __launch_bounds__(512) void fused_gemm(
    const unsigned short* __restrict__ A,
    const unsigned short* __restrict__ Wb,
    const float* __restrict__ pos_table, const float* __restrict__ conv_b,
    const float* __restrict__ ln_w, const float* __restrict__ ln_b,
    float* __restrict__ out, float4* __restrict__ out4)
{
    const int bid = blockIdx.x;
    const int t = threadIdx.x;

    if (bid < GEMM_BLOCKS) {
        const int m0   = bid * 32;
        const int wave = t >> 6;
        const int lane = t & 63;
        const int l16  = lane & 15, q = lane >> 4;
        const int ncol0 = wave * 160;

        // ---- K-loop: register double-buffered, fragments straight from L2
        f32x4 acc[2][10] = {};
        const unsigned short* ap = A  + (size_t)(m0 + l16) * KPAD + q * 8;
        const unsigned short* bp = Wb + (size_t)(ncol0 + l16) * KPAD + q * 8;

        bf16x8 ab[2][2], bb[2][10];
        #pragma unroll
        for (int mi = 0; mi < 2; ++mi) ab[0][mi] = *(const bf16x8*)(ap + mi * 16 * KPAD);
        #pragma unroll
        for (int ni = 0; ni < 10; ++ni) bb[0][ni] = *(const bf16x8*)(bp + ni * 16 * KPAD);

        #pragma unroll
        for (int kki = 0; kki < 19; ++kki) {
            const int cur = kki & 1, nxt = cur ^ 1;
            if (kki < 18) {
                const unsigned short* apn = ap + (kki + 1) * 32;
                const unsigned short* bpn = bp + (kki + 1) * 32;
                #pragma unroll
                for (int mi = 0; mi < 2; ++mi) ab[nxt][mi] = *(const bf16x8*)(apn + mi * 16 * KPAD);
                #pragma unroll
                for (int ni = 0; ni < 10; ++ni) bb[nxt][ni] = *(const bf16x8*)(bpn + ni * 16 * KPAD);
            }
            #pragma unroll
            for (int mi = 0; mi < 2; ++mi)
                #pragma unroll
                for (int ni = 0; ni < 10; ++ni)
                    acc[mi][ni] = __builtin_amdgcn_mfma_f32_16x16x32_bf16(
                        ab[cur][mi], bb[cur][ni], acc[mi][ni], 0, 0, 0);
        }

        // ---- block-uniform image geometry (all boundaries divisible by 32)
        int img     = (m0 < 1024) ? 0 : (m0 < 2560) ? 1 : (m0 < 3136) ? 2 : (m0 < 3648) ? 3 : (m0 < 5248) ? 4 : 5;
        int rowOff  = (img == 0) ? 0 : (img == 1) ? 1024 : (img == 2) ? 2560 : (img == 3) ? 3136 : (img == 4) ? 3648 : 5248;
        int h       = (img == 0) ? 32 : (img == 1) ? 32 : (img == 2) ? 24 : (img == 3) ? 16 : (img == 4) ? 40 : 24;
        int w       = (img == 0) ? 32 : (img == 1) ? 48 : (img == 2) ? 24 : (img == 3) ? 32 : (img == 4) ? 40 : 32;
        int outBase = (img == 0) ? 0 : (img == 1) ? 2048 : (img == 2) ? 4096 : (img == 3) ? 4672 : (img == 4) ? 6144 : 8192;
        unsigned int magic = (unsigned int)((1u << 22) / (unsigned)w) + 1u;
        float sh = 32.0f / (float)h, sw = 32.0f / (float)w;

        // hoist per-column params (10 cols per lane)
        float cbv[10], gv[10], bev[10];
        #pragma unroll
        for (int ni = 0; ni < 10; ++ni) {
            int col = ncol0 + ni * 16 + l16;
            cbv[ni] = conv_b[col];
            gv[ni]  = ln_w[col];
            bev[ni] = ln_b[col];
        }

        __shared__ float part_s[8][32], part_s2[8][32], ln_m[32], ln_i[32];

        // pass 1: add conv_b + pos, per-row stats
        #pragma unroll
        for (int mi = 0; mi < 2; ++mi) {
            #pragma unroll
            for (int reg = 0; reg < 4; ++reg) {
                int row_t = mi * 16 + q * 4 + reg;
                int ri = m0 + row_t - rowOff;
                unsigned int y = ((unsigned int)ri * magic) >> 22;
                int x = ri - (int)y * w;
                float cy = fminf(fmaxf(((float)y + 0.5f) * sh - 0.5f, 0.0f), 31.0f);
                float cx = fminf(fmaxf(((float)x + 0.5f) * sw - 0.5f, 0.0f), 31.0f);
                int y0 = (int)cy; int y1 = min(y0 + 1, 31); float wy = cy - (float)y0;
                int x0 = (int)cx; int x1 = min(x0 + 1, 31); float wx = cx - (float)x0;
                float w00 = (1.f - wy) * (1.f - wx), w01 = (1.f - wy) * wx;
                float w10 = wy * (1.f - wx),         w11 = wy * wx;
                const float* P00 = pos_table + (size_t)(1 + y0*32 + x0) * E_DIM;
                const float* P01 = pos_table + (size_t)(1 + y0*32 + x1) * E_DIM;
                const float* P10 = pos_table + (size_t)(1 + y1*32 + x0) * E_DIM;
                const float* P11 = pos_table + (size_t)(1 + y1*32 + x1) * E_DIM;
                float s = 0.f, s2 = 0.f;
                #pragma unroll
                for (int ni = 0; ni < 10; ++ni) {
                    int col = ncol0 + ni * 16 + l16;
                    float p = w00*P00[col] + w01*P01[col] + w10*P10[col] + w11*P11[col];
                    float v = acc[mi][ni][reg] + cbv[ni] + p;
                    acc[mi][ni][reg] = v;
                    s += v; s2 += v * v;
                }
                #pragma unroll
                for (int msk = 1; msk < 16; msk <<= 1) {
                    s  += __shfl_xor(s,  msk, 64);
                    s2 += __shfl_xor(s2, msk, 64);
                }
                if (l16 == 0) { part_s[wave][row_t] = s; part_s2[wave][row_t] = s2; }
            }
        }
        __syncthreads();
        if (t < 32) {
            float S = 0.f, S2 = 0.f;
            #pragma unroll
            for (int w2 = 0; w2 < 8; ++w2) { S += part_s[w2][t]; S2 += part_s2[w2][t]; }
            float mean = S / 1280.f;
            float var  = S2 / 1280.f - mean * mean;
            ln_m[t] = mean;
            ln_i[t] = 1.f / sqrtf(var + 1e-5f);
        }
        __syncthreads();

        // pass 2: normalize + scatter
        #pragma unroll
        for (int mi = 0; mi < 2; ++mi) {
            #pragma unroll
            for (int reg = 0; reg < 4; ++reg) {
                int row_t = mi * 16 + q * 4 + reg;
                int ri = m0 + row_t - rowOff;
                float mean = ln_m[row_t], inv = ln_i[row_t];
                float* orow = out + (size_t)(outBase + ri) * E_DIM;
                #pragma unroll
                for (int ni = 0; ni < 10; ++ni) {
                    int col = ncol0 + ni * 16 + l16;
                    orow[col] = (acc[mi][ni][reg] - mean) * inv * gv[ni] + bev[ni];
                }
            }
        }
    } else if (bid < GEMM_BLOCKS + ZERO_BLOCKS2) {
        // zero unfilled emb rows: 4224 rows x 320 float4 = 1,351,680 f4
        int base = (bid - GEMM_BLOCKS) * 2048 + t;
        #pragma unroll
        for (int j = 0; j < 4; ++j) {
            int idx = base + j * 512;
            int zrow = idx / 320;
            int c4   = idx - zrow * 320;
            int b, rowInB;
            if      (zrow < 1024) { b = 0; rowInB = 1024 + zrow; }
            else if (zrow < 1536) { b = 1; rowInB = 1536 + (zrow - 1024); }
            else if (zrow < 2496) { b = 2; rowInB = 1088 + (zrow - 1536); }
            else if (zrow < 2944) { b = 3; rowInB = 1600 + (zrow - 2496); }
            else                  { b = 4; rowInB =  768 + (zrow - 2944); }
            size_t o4 = ((size_t)(b * 2048 + rowInB) * E_DIM) / 4 + c4;
            out4[o4] = make_float4(0.f, 0.f, 0.f, 0.f);
        }
    } else {
        // mask fill: 5 x 2048 x 512 float4
        int base = (bid - GEMM_BLOCKS - ZERO_BLOCKS2) * 2048 + t;
        #pragma unroll
        for (int j = 0; j < 4; ++j) {
            int m4 = base + j * 512;
            int b  = m4 >> 20;
            int rr = (m4 >> 9) & 2047;
            int c0 = (m4 & 511) * 4;
            int h0 = (b == 0) ? 1024 : (b == 1) ? 1536 : (b == 2) ? 576 : (b == 3) ? 1600 : 768;
            bool on = (rr < h0 && c0 < h0);
            if (b == 2) on = on || (rr >= 576 && rr < 1088 && c0 >= 576 && c0 < 1088);
            float f = on ? 1.f : 0.f;
            out4[(size_t)(EMB_FLOATS / 4) + m4] = make_float4(f, f, f, f);
        }
    }
}

// ---------------------------------------------------------------------------
extern "C" void kernel_launch(void* const* d_in, const int* in_sizes, int n_in,
                              void* d_out, int out_size, void* d_ws, size_t ws_size,
                              hipStream_t stream) {
    const float* img0 = (const float*)d_in[0];
    const float* img1 = (const float*)d_in[1];
    const float* img2 = (const float*)d_in[2];
    const float* img3 = (const float*)d_in[3];
    const float* img4 = (const float*)d_in[4];
    const float* img5 = (const float*)d_in[5];
    const float* conv_w    = (const float*)d_in[6];
    const float* conv_b    = (const float*)d_in[7];
    const float* pos_table = (const float*)d_in[8];
    const float* ln_w      = (const float*)d_in[9];
    const float* ln_b      = (const float*)d_in[10];
    float* out = (float*)d_out;

    unsigned short* Abf = (unsigned short*)d_ws;                 // 7.3 MB
    unsigned short* Wbf = Abf + (size_t)M_TOTAL * KPAD;          // 1.5 MB

    prep<<<PREP_BLOCKS, 256, 0, stream>>>(
        img0, img1, img2, img3, img4, img5, conv_w, (us4*)Abf, (us4*)Wbf);

    fused_gemm<<<FUSED_BLOCKS, 512, 0, stream>>>(
        Abf, Wbf, pos_table, conv_b, ln_w, ln_b, out, (float4*)out);
}